// Round 5
// baseline (384.256 us; speedup 1.0000x reference)
//
#include <hip/hip_runtime.h>
#include <stdint.h>

typedef short s16x8 __attribute__((ext_vector_type(8)));
typedef float f32x4 __attribute__((ext_vector_type(4)));
typedef unsigned long long u64;

#define IN_F   256
#define OUT_F  256
#define BATCH  16384
#define NB     31
#define KONE   8192
#define KTOT   8448

__device__ __forceinline__ unsigned short f2bf(float f) {
    unsigned u = __float_as_uint(f);
    u += 0x7FFFu + ((u >> 16) & 1u);   // RNE
    return (unsigned short)(u >> 16);
}

// ---------------- kernel 1: fused prep --------------------------------------
// blk 0..255  : column min/max partials over 64 rows each -> pmn/pmx[256][256]
// blk 256..511: Haar-synthesize Wb row o = blk-256
// blk 512..767: zero a 64KB slice of out (K-split atomics accumulate into it)
__global__ __launch_bounds__(256) void prep1(
    const float* __restrict__ x, const float* __restrict__ bw,
    const float* __restrict__ sw, const float* __restrict__ sc,
    float* __restrict__ pmn, float* __restrict__ pmx,
    unsigned short* __restrict__ Wb, float* __restrict__ outz) {
    const int blk = blockIdx.x, t = threadIdx.x;
    if (blk < 256) {
        const int b0 = blk * 64;
        float mn = 3.4e38f, mx = -3.4e38f;
        for (int r = 0; r < 64; ++r) {
            float v = x[(size_t)(b0 + r) * IN_F + t];
            mn = fminf(mn, v);
            mx = fmaxf(mx, v);
        }
        pmn[blk * 256 + t] = mn;
        pmx[blk * 256 + t] = mx;
    } else if (blk < 512) {
        const int o = blk - 256, i = t;
        const float s = sc[o * IN_F + i];
        const float* swp = sw + (size_t)(o * IN_F + i) * NB;
        float w[NB];
#pragma unroll
        for (int k = 0; k < NB; ++k) w[k] = swp[k];
        unsigned short* dst = Wb + (size_t)o * KTOT + i * 32;
#pragma unroll
        for (int q = 0; q < 4; ++q) {
            union { s16x8 v; unsigned short s8[8]; } pk;
#pragma unroll
            for (int e = 0; e < 8; ++e) {
                int j = q * 8 + e;
                float acc = 0.f;
#pragma unroll
                for (int l = 0; l < 5; ++l) {
                    int kk = (1 << l) - 1 + (j >> (5 - l));
                    acc += (((j >> (4 - l)) & 1) ? -w[kk] : w[kk]);
                }
                pk.s8[e] = f2bf(acc * s);
            }
            *(s16x8*)(dst + q * 8) = pk.v;
        }
        Wb[(size_t)o * KTOT + KONE + i] = f2bf(bw[o * IN_F + i]);
    } else {
        float4 z; z.x = z.y = z.z = z.w = 0.f;
        float4* oz = (float4*)outz + (size_t)(blk - 512) * 4096;
#pragma unroll
        for (int r = 0; r < 16; ++r) oz[t + r * 256] = z;
    }
}

// ---------------- kernel 2: fused [reduce partials] + leaf indices ----------
// Each block redundantly reduces all 256 partial rows (coalesced, L2-resident,
// ~1KB/thread) -> xmin/rden in LDS, then computes its 64 rows of lt[b][i].
// Saves one launch gap + the xminF/rdenF global round-trip.
__global__ __launch_bounds__(256) void leaf2(
    const float* __restrict__ x, const float* __restrict__ pmn,
    const float* __restrict__ pmx, unsigned char* __restrict__ lt) {
    __shared__ float xminsh[IN_F], rdnsh[IN_F];
    const int t = threadIdx.x;
    {
        float mn0 = 3.4e38f, mn1 = 3.4e38f, mx0 = -3.4e38f, mx1 = -3.4e38f;
#pragma unroll 8
        for (int b = 0; b < 256; b += 2) {
            mn0 = fminf(mn0, pmn[(size_t)b * 256 + t]);
            mn1 = fminf(mn1, pmn[(size_t)(b + 1) * 256 + t]);
            mx0 = fmaxf(mx0, pmx[(size_t)b * 256 + t]);
            mx1 = fmaxf(mx1, pmx[(size_t)(b + 1) * 256 + t]);
        }
        float mn = fminf(mn0, mn1), mx = fmaxf(mx0, mx1);
        xminsh[t] = mn;
        rdnsh[t] = 1.0f / (mx - mn + 1e-8f);   // verified chain: rcp-mult
    }
    __syncthreads();
    const int lane = t & 63, w = t >> 6;
    const int b0 = blockIdx.x * 64;
    const float4 mn = *(const float4*)(xminsh + lane * 4);
    const float4 rd = *(const float4*)(rdnsh + lane * 4);
#pragma unroll 4
    for (int r = 0; r < 16; ++r) {
        int row = b0 + w * 16 + r;
        float4 v = *(const float4*)(x + (size_t)row * IN_F + lane * 4);
        unsigned b[4];
        float xs[4] = {v.x, v.y, v.z, v.w};
        float ms[4] = {mn.x, mn.y, mn.z, mn.w};
        float rs[4] = {rd.x, rd.y, rd.z, rd.w};
#pragma unroll
        for (int e = 0; e < 4; ++e) {
            float xn = (xs[e] - ms[e]) * rs[e];
            int l = (int)(xn * 32.0f);
            b[e] = (l >= 0 && l < 32) ? (unsigned)l : 255u;
        }
        unsigned pk = b[0] | (b[1] << 8) | (b[2] << 16) | (b[3] << 24);
        *(unsigned*)(lt + (size_t)row * IN_F + lane * 4) = pk;
    }
}

// ---------------- kernel 4: ZERO-LDS one-hot GEMM, B global->register -------
// Every prior variant (lockstep shared-LDS: 89.7/94/97.5us; wave-private LDS:
// 134us) pinned MfmaUtil at 21-32% on the glds->barrier/vmcnt->ds_read round
// trip. Here the B fragment (16 contiguous bytes of Wb) loads straight into
// VGPRs: no LDS, no barriers, no glds. Compiler auto-inserts counted vmcnt for
// reg loads (its strength). Wave tile M64xN32 (mt=4,nt=2), dbuf B regs, ~115
// VGPR -> 4 waves/SIMD, all free-running. ks pair shares 128B cachelines; each
// XCD's B slice (128 N-cols x half-K) = 1.1MB, L2-resident via XCD-contiguous
// sid. A-synth identity / K order / z-split+atomics byte-identical to R3/R4.
__global__ __launch_bounds__(256, 4) void gemm_kan(
    const float* __restrict__ x,
    const unsigned short* __restrict__ Wb,
    const unsigned char* __restrict__ lt,
    float* __restrict__ out)
{
    const int t    = threadIdx.x;
    const int lane = t & 63;
    const int wv   = t >> 6;           // 0..3

    // XCD-contiguous: XCD k hosts sids k*128..k*128+127 = one (nblk,zz) range
    const int bid   = blockIdx.x;
    const int sid   = (bid & 7) * 128 + (bid >> 3);
    const int mtile = sid & 255;
    const int nblk  = (sid >> 8) & 1;
    const int zz    = sid >> 9;
    const int kbeg  = zz ? 68 : 0;
    const int kend  = zz ? 132 : 68;

    const int rr = lane & 15, kq = lane >> 4;
    const int mbase = mtile * 64;
    const int nb    = nblk * 128 + wv * 32;

    // B fragment pointers: lane covers N-rows nb+rr (nt=0) and nb+16+rr (nt=1);
    // frag(ks,nt) at kb = 16B at bpN + kb*64 + ks*32 (elements)
    const unsigned short* bp0 = Wb + (size_t)(nb + rr) * KTOT + kq * 8;
    const unsigned short* bp1 = bp0 + (size_t)16 * KTOT;
    const unsigned char*  lpr = lt + (size_t)(mbase + rr) * IN_F;

    f32x4 acc[4][2] = {};
    s16x8 bA[2][2], bB[2][2];          // [ks][nt] double-buffered B frags

#define LOADB(KB, DST) {                                                       \
        const unsigned short* _p0 = bp0 + (size_t)(KB) * 64;                   \
        const unsigned short* _p1 = bp1 + (size_t)(KB) * 64;                   \
        DST[0][0] = *(const s16x8*)_p0;                                        \
        DST[1][0] = *(const s16x8*)(_p0 + 32);                                 \
        DST[0][1] = *(const s16x8*)_p1;                                        \
        DST[1][1] = *(const s16x8*)(_p1 + 32);                                 \
    }

    u64 Lc[4], Ln[4];
#pragma unroll
    for (int mt = 0; mt < 4; ++mt)
        Lc[mt] = *(const u64*)(lpr + (size_t)mt * 16 * IN_F + 2 * kbeg);
    LOADB(kbeg, bA);

    for (int kb0 = kbeg; kb0 < kend; kb0 += 4) {
        // prefetch next leaf group (reg loads; land under MFMA)
#pragma unroll
        for (int mt = 0; mt < 4; ++mt) Ln[mt] = Lc[mt];
        if (kb0 + 4 < kend && kb0 + 4 < 128) {
#pragma unroll
            for (int mt = 0; mt < 4; ++mt)
                Ln[mt] = *(const u64*)(lpr + (size_t)mt * 16 * IN_F + 2 * (kb0 + 4));
        }
        const bool denseg = (kb0 >= 128);

        // j unrolled with named buffers (static indexing; rule #20)
#define STEP(CUR, NXT, J) {                                                    \
        const int kb = kb0 + (J);                                              \
        if (kb + 1 < kend) LOADB(kb + 1, NXT);                                 \
        _Pragma("unroll")                                                      \
        for (int ks = 0; ks < 2; ++ks) {                                       \
            s16x8 af[4];                                                       \
            if (!denseg) {                                                     \
                _Pragma("unroll")                                              \
                for (int mt = 0; mt < 4; ++mt) {                               \
                    const int L = (int)((Lc[mt] >> ((((J) << 1) | ks) << 3)) & 255u); \
                    unsigned hot = ((L >> 3) == kq) ? (0x3F80u << ((L & 1) << 4)) : 0u; \
                    int slot = (L >> 1) & 3;                                   \
                    union { s16x8 v; unsigned u[4]; } a;                       \
                    a.u[0] = (slot == 0) ? hot : 0u;                           \
                    a.u[1] = (slot == 1) ? hot : 0u;                           \
                    a.u[2] = (slot == 2) ? hot : 0u;                           \
                    a.u[3] = (slot == 3) ? hot : 0u;                           \
                    af[mt] = a.v;                                              \
                }                                                              \
            } else {                                                           \
                _Pragma("unroll")                                              \
                for (int mt = 0; mt < 4; ++mt) {                               \
                    const float* xr = x + (size_t)(mbase + mt * 16 + rr) * IN_F \
                                        + (kb - 128) * 64 + ks * 32 + kq * 8;  \
                    union { s16x8 v; unsigned short s8[8]; } a;                \
                    _Pragma("unroll")                                          \
                    for (int e = 0; e < 8; ++e) a.s8[e] = f2bf(fmaxf(xr[e], 0.0f)); \
                    af[mt] = a.v;                                              \
                }                                                              \
            }                                                                  \
            __builtin_amdgcn_s_setprio(1);                                     \
            _Pragma("unroll")                                                  \
            for (int mt = 0; mt < 4; ++mt)                                     \
                _Pragma("unroll")                                              \
                for (int nt = 0; nt < 2; ++nt)                                 \
                    acc[mt][nt] = __builtin_amdgcn_mfma_f32_16x16x32_bf16(     \
                        af[mt], CUR[ks][nt], acc[mt][nt], 0, 0, 0);            \
            __builtin_amdgcn_s_setprio(0);                                     \
        }                                                                      \
    }
        STEP(bA, bB, 0);
        STEP(bB, bA, 1);
        STEP(bA, bB, 2);
        STEP(bB, bA, 3);
#undef STEP
#pragma unroll
        for (int mt = 0; mt < 4; ++mt) Lc[mt] = Ln[mt];
    }
#undef LOADB

    // epilogue: C/D layout col=lane&15, row=(lane>>4)*4+reg; K-split -> atomicAdd
    const int rq = lane >> 4;
#pragma unroll
    for (int mt = 0; mt < 4; ++mt)
#pragma unroll
        for (int nt = 0; nt < 2; ++nt)
#pragma unroll
            for (int v = 0; v < 4; ++v) {
                int row = mbase + mt * 16 + rq * 4 + v;
                int col = nb + nt * 16 + rr;
                atomicAdd(&out[(size_t)row * OUT_F + col], acc[mt][nt][v]);
            }
}

// ---------------- host ----------------
extern "C" void kernel_launch(void* const* d_in, const int* in_sizes, int n_in,
                              void* d_out, int out_size, void* d_ws, size_t ws_size,
                              hipStream_t stream) {
    (void)in_sizes; (void)n_in; (void)out_size; (void)ws_size;
    const float* x  = (const float*)d_in[0];   // [16384,256]
    const float* bw = (const float*)d_in[1];   // [256,256]
    const float* sw = (const float*)d_in[2];   // [256,256,31]
    const float* sc = (const float*)d_in[3];   // [256,256]
    float* out = (float*)d_out;

    char* ws = (char*)d_ws;
    unsigned short* Wb = (unsigned short*)ws;               // 4,325,376 B
    unsigned char*  lt = (unsigned char*)(ws + 4325376);    // 4,194,304 B  [b][i]
    // partials NOT aliased with lt (leaf2 reads them while writing lt)
    float* pmn = (float*)(ws + 8519680);                    // 262,144 B
    float* pmx = (float*)(ws + 8781824);                    // 262,144 B
    // total ws use: 9,043,968 B

    prep1<<<768, 256, 0, stream>>>(x, bw, sw, sc, pmn, pmx, Wb, out);
    leaf2<<<256, 256, 0, stream>>>(x, pmn, pmx, lt);
    gemm_kan<<<1024, 256, 0, stream>>>(x, Wb, lt, out);
}

// Round 6
// 168.394 us; speedup vs baseline: 2.2819x; 2.2819x over previous
//
#include <hip/hip_runtime.h>
#include <stdint.h>

typedef short s16x8 __attribute__((ext_vector_type(8)));
typedef float f32x4 __attribute__((ext_vector_type(4)));

#define IN_F   256
#define OUT_F  256
#define BATCH  16384
#define NB     31
#define KONE   8192
#define KTOT   8448

typedef const __attribute__((address_space(1))) void* as1cvp;
typedef __attribute__((address_space(3))) void* as3vp;

__device__ __forceinline__ unsigned short f2bf(float f) {
    unsigned u = __float_as_uint(f);
    u += 0x7FFFu + ((u >> 16) & 1u);   // RNE
    return (unsigned short)(u >> 16);
}

// ---------------- kernel 1: fused prep --------------------------------------
// blk 0..255  : column min/max partials over 64 rows -> pmn/pmx[256][256]
// blk 256..511: Haar-synthesize Wb row o = blk-256 (weights loaded once)
__global__ __launch_bounds__(256) void prep1(
    const float* __restrict__ x, const float* __restrict__ bw,
    const float* __restrict__ sw, const float* __restrict__ sc,
    float* __restrict__ pmn, float* __restrict__ pmx,
    unsigned short* __restrict__ Wb) {
    const int blk = blockIdx.x, t = threadIdx.x;
    if (blk < 256) {
        const int b0 = blk * 64;
        float mn = 3.4e38f, mx = -3.4e38f;
        for (int r = 0; r < 64; ++r) {
            float v = x[(size_t)(b0 + r) * IN_F + t];
            mn = fminf(mn, v);
            mx = fmaxf(mx, v);
        }
        pmn[blk * 256 + t] = mn;
        pmx[blk * 256 + t] = mx;
    } else {
        const int o = blk - 256, i = t;
        const float s = sc[o * IN_F + i];
        const float* swp = sw + (size_t)(o * IN_F + i) * NB;
        float w[NB];
#pragma unroll
        for (int k = 0; k < NB; ++k) w[k] = swp[k];
        unsigned short* dst = Wb + (size_t)o * KTOT + i * 32;
#pragma unroll
        for (int q = 0; q < 4; ++q) {
            union { s16x8 v; unsigned short s8[8]; } pk;
#pragma unroll
            for (int e = 0; e < 8; ++e) {
                int j = q * 8 + e;
                float acc = 0.f;
#pragma unroll
                for (int l = 0; l < 5; ++l) {
                    int kk = (1 << l) - 1 + (j >> (5 - l));
                    acc += (((j >> (4 - l)) & 1) ? -w[kk] : w[kk]);
                }
                pk.s8[e] = f2bf(acc * s);
            }
            *(s16x8*)(dst + q * 8) = pk.v;
        }
        Wb[(size_t)o * KTOT + KONE + i] = f2bf(bw[o * IN_F + i]);
    }
}

// ---------------- kernel 2: fused [redundant reduce] + transposed leaves ----
// Each block reduces all 256 partial rows (coalesced, L2-resident) -> xmin/rden
// in LDS, then computes its 64 rows into TRANSPOSED lt[i][b] (R1-verified
// stride-68 LDS transpose; transposed layout keeps the gemm's leaf loads
// coalesced). Chain verified: xn=(x-xmin)*rden, leaf=(int)(xn*32), else 255.
__global__ __launch_bounds__(256) void leaf2t(
    const float* __restrict__ x, const float* __restrict__ pmn,
    const float* __restrict__ pmx, unsigned char* __restrict__ lt) {
    __shared__ unsigned char lsh[256 * 68];    // [i][r], stride 68 (odd dword)
    __shared__ float xminsh[IN_F], rdnsh[IN_F];
    const int t = threadIdx.x;
    {
        float mn0 = 3.4e38f, mn1 = 3.4e38f, mx0 = -3.4e38f, mx1 = -3.4e38f;
#pragma unroll 8
        for (int b = 0; b < 256; b += 2) {
            mn0 = fminf(mn0, pmn[(size_t)b * 256 + t]);
            mn1 = fminf(mn1, pmn[(size_t)(b + 1) * 256 + t]);
            mx0 = fmaxf(mx0, pmx[(size_t)b * 256 + t]);
            mx1 = fmaxf(mx1, pmx[(size_t)(b + 1) * 256 + t]);
        }
        float mn = fminf(mn0, mn1), mx = fmaxf(mx0, mx1);
        xminsh[t] = mn;
        rdnsh[t] = 1.0f / (mx - mn + 1e-8f);   // verified chain: rcp-mult
    }
    __syncthreads();
    const float xmn = xminsh[t], rdn = rdnsh[t];
    const int b0 = blockIdx.x * 64;
    for (int r = 0; r < 64; ++r) {
        float v = x[(size_t)(b0 + r) * IN_F + t];
        float xn = (v - xmn) * rdn;
        int l = (int)(xn * 32.0f);
        lsh[t * 68 + r] = (l >= 0 && l < 32) ? (unsigned char)l : (unsigned char)255;
    }
    __syncthreads();
    const int lane = t & 63, w = t >> 6;
    const unsigned* lshU = (const unsigned*)lsh;   // row i = lshU[i*17 .. +15]
#pragma unroll
    for (int ib = 0; ib < 16; ++ib) {
        int i = ib * 16 + w * 4 + (lane >> 4);
        unsigned val = lshU[i * 17 + (lane & 15)];
        *(unsigned*)(lt + (size_t)i * BATCH + b0 + (lane & 15) * 4) = val;
    }
}

// ---------------- kernel 3: one-hot GEMM, R1 structure, ONE barrier/kb ------
// Session evidence: lockstep shared-LDS 2-wave = 89.7us (best); 4-wave = 97.5;
// reg-A = 94; wave-private LDS = 134; zero-LDS = 307. This is the measured-best
// R1 kernel with its B1 barrier DELETED: the A one-hot tile is wave-private by
// construction (wave w writes rows 32w..+31 via am=t>>1; MFMA reads only rows
// 32wv+mt*16+rr -- its own half), so A write->read ordering is program order +
// lgkmcnt within one wave. The dense tail is rewritten wave-private (wave w
// overwrites only rows 32w..+31) to keep that invariant. Only the B double
// buffer is cross-wave -> ONE __syncthreads per kb (after MFMA) remains; its
// vmcnt(0) drain is cheap (glds issued pre-MFMA, ~700cy of cover). All math,
// swizzles, fragment layouts, K-order bit-identical to the verified R1 kernel.
__global__ __launch_bounds__(128, 2) void gemm_kan(
    const float* __restrict__ x,
    const unsigned short* __restrict__ Wb,
    const unsigned char* __restrict__ lt,
    float* __restrict__ out)
{
    __shared__ unsigned short Ash[64 * 64];        // 8KB, XOR-swizzled chunks
    __shared__ unsigned short Bsh[2 * 64 * 64];    // 16KB double buffer

    const int t     = threadIdx.x;     // 0..127
    const int lane  = t & 63;
    const int wv    = t >> 6;          // 0,1
    const int mtile = blockIdx.x;
    const int ntile = blockIdx.y;

    // zero A tile: each wave zeroes ITS OWN 32 rows (wave-private invariant)
    {
        uint4 z; z.x = z.y = z.z = z.w = 0u;
        uint4* a4 = (uint4*)(Ash + wv * 2048);
#pragma unroll
        for (int r = 0; r < 4; ++r) a4[lane + r * 64] = z;
    }

    // B glds source base (pre-swizzled: n&7 == lane>>3, q-independent);
    // wave wv stages N-rows 32wv..+31 into Bsh[buf][wv*2048..]
    const unsigned char* bbase = (const unsigned char*)(Wb
        + (size_t)(ntile * 64 + wv * 32 + (lane >> 3)) * KTOT
        + (((lane & 7) ^ (lane >> 3)) << 3));

    // one-hot identities: thread -> (tile row am, feature ag); wave-private rows
    const int am = t >> 1;             // 0..63; wave0 -> 0..31, wave1 -> 32..63
    const int ag = t & 1;
    const size_t lrow0 = (size_t)mtile * 64;
    int ps = -1;

    unsigned char lf = lt[(size_t)ag * BATCH + lrow0 + am];

    // prologue: stage B(0) into buf0
#pragma unroll
    for (int q = 0; q < 4; ++q)
        __builtin_amdgcn_global_load_lds(
            (as1cvp)(bbase + (size_t)q * 8 * KTOT * 2),
            (as3vp)(uint32_t)(uintptr_t)(Bsh + wv * 2048 + q * 512), 16, 0, 0);
    __syncthreads();   // drains B(0); covers A-zero too

    f32x4 acc[2][4] = {};
    const int rr = lane & 15, kq = lane >> 4;

    for (int kb = 0; kb < 132; ++kb) {
        const int cur = kb & 1;
        // ---- A phase (wave-private; NO barrier after) ----
        if (kb < 128) {
            if (ps >= 0) Ash[ps] = 0;
            int l = lf;
            if (l < 32) {
                int c = (ag << 2) + (l >> 3);
                ps = (am << 6) + ((c ^ (am & 7)) << 3) + (l & 7);
                Ash[ps] = 0x3F80;
            } else ps = -1;
        } else {
            // dense relu(x) tail: wave wv overwrites ONLY rows 32wv..+31
            const float* xr = x + (size_t)(mtile * 64 + wv * 32) * IN_F + (kb - 128) * 64 + lane;
            const int cslot = (lane >> 3);
#pragma unroll
            for (int m0 = 0; m0 < 32; ++m0) {
                int m = wv * 32 + m0;
                float v = xr[(size_t)m0 * IN_F];
                Ash[(m << 6) + ((cslot ^ (m & 7)) << 3) + (lane & 7)] = f2bf(fmaxf(v, 0.0f));
            }
        }

        // ---- issue B(kb+1) into alt buffer (overlaps MFMA below) ----
        if (kb + 1 < 132) {
            const unsigned char* src = bbase + (size_t)(kb + 1) * 128;
            unsigned short* dst = Bsh + (1 - cur) * 4096 + wv * 2048;
#pragma unroll
            for (int q = 0; q < 4; ++q)
                __builtin_amdgcn_global_load_lds(
                    (as1cvp)(src + (size_t)q * 8 * KTOT * 2),
                    (as3vp)(uint32_t)(uintptr_t)(dst + q * 512), 16, 0, 0);
        }
        // prefetch leaf byte for kb+1 (lands under MFMA)
        if (kb + 1 < 128) {
            lf = lt[(size_t)((kb + 1) * 2 + ag) * BATCH + lrow0 + am];
        }

        // ---- MFMA on buf[cur]: wave wv does rows 32wv..+31 ----
        const unsigned short* bb = Bsh + cur * 4096;
#pragma unroll
        for (int ks = 0; ks < 2; ++ks) {
            const int c = (ks << 2) + kq;
            s16x8 af[2], bfr[4];
#pragma unroll
            for (int mt = 0; mt < 2; ++mt) {
                int m = wv * 32 + mt * 16 + rr;
                af[mt] = *(const s16x8*)&Ash[(m << 6) + ((c ^ (m & 7)) << 3)];
            }
#pragma unroll
            for (int nt = 0; nt < 4; ++nt) {
                int n = nt * 16 + rr;
                bfr[nt] = *(const s16x8*)&bb[(n << 6) + ((c ^ (n & 7)) << 3)];
            }
#pragma unroll
            for (int mt = 0; mt < 2; ++mt)
#pragma unroll
                for (int nt = 0; nt < 4; ++nt)
                    acc[mt][nt] = __builtin_amdgcn_mfma_f32_16x16x32_bf16(
                        af[mt], bfr[nt], acc[mt][nt], 0, 0, 0);
        }
        __syncthreads();   // single barrier: B(kb+1) drained, dbuf swap safe
    }

    // ---- epilogue: C/D layout col=lane&15, row=(lane>>4)*4+reg (m89/m91) ----
    const int rq = lane >> 4;
#pragma unroll
    for (int mt = 0; mt < 2; ++mt)
#pragma unroll
        for (int nt = 0; nt < 4; ++nt)
#pragma unroll
            for (int v = 0; v < 4; ++v) {
                int row = mtile * 64 + wv * 32 + mt * 16 + rq * 4 + v;
                int col = ntile * 64 + nt * 16 + rr;
                out[(size_t)row * OUT_F + col] = acc[mt][nt][v];
            }
}

// ---------------- host ----------------
extern "C" void kernel_launch(void* const* d_in, const int* in_sizes, int n_in,
                              void* d_out, int out_size, void* d_ws, size_t ws_size,
                              hipStream_t stream) {
    (void)in_sizes; (void)n_in; (void)out_size; (void)ws_size;
    const float* x  = (const float*)d_in[0];   // [16384,256]
    const float* bw = (const float*)d_in[1];   // [256,256]
    const float* sw = (const float*)d_in[2];   // [256,256,31]
    const float* sc = (const float*)d_in[3];   // [256,256]
    float* out = (float*)d_out;

    char* ws = (char*)d_ws;
    unsigned short* Wb = (unsigned short*)ws;               // 4,325,376 B
    unsigned char*  lt = (unsigned char*)(ws + 4325376);    // 4,194,304 B  [i][b]
    float* pmn = (float*)(ws + 8519680);                    // 262,144 B
    float* pmx = (float*)(ws + 8781824);                    // 262,144 B

    prep1<<<512, 256, 0, stream>>>(x, bw, sw, sc, pmn, pmx, Wb);
    leaf2t<<<256, 256, 0, stream>>>(x, pmn, pmx, lt);
    gemm_kan<<<dim3(256, 4), 128, 0, stream>>>(x, Wb, lt, out);
}